// Round 1
// baseline (230.859 us; speedup 1.0000x reference)
//
#include <hip/hip_runtime.h>
#include <stdint.h>

typedef unsigned int u32;
typedef unsigned long long u64;

#define NW      147456   // 128*128*9
#define HW      3136     // 56*56
#define PADW    58

// ---------------------------------------------------------------------------
// Kernel 1: weight synthesis + sign-pack.
// sign(w) = sign(m + rv.z) since the rsqrt normalizer is positive.
// Wave lanes = input channels (group of 64); ballot packs 64 sign bits.
// Layout: wb[(o*9+tap)*4 + word], word = channel/32 (0..3), bit = channel%32.
__global__ __launch_bounds__(256) void k_wsynth(
    const float* __restrict__ M, const float* __restrict__ Z,
    const float* __restrict__ rv, u32* __restrict__ wb)
{
  int gid  = blockIdx.x * 256 + threadIdx.x;
  int wid  = gid >> 6;                 // 0..2303  (= 128 o * 9 tap * 2 grp)
  int lane = threadIdx.x & 63;
  int o    = wid / 18;
  int r    = wid - o * 18;
  int tap  = r >> 1;
  int g    = r & 1;
  int i    = g * 64 + lane;            // input channel
  int idx  = o * 1152 + i * 9 + tap;   // flat (o,i,kh,kw)

  float t = M[idx];
  t = fmaf(rv[0], Z[0 * NW + idx], t);
  t = fmaf(rv[1], Z[1 * NW + idx], t);
  t = fmaf(rv[2], Z[2 * NW + idx], t);
  t = fmaf(rv[3], Z[3 * NW + idx], t);
  t = fmaf(rv[4], Z[4 * NW + idx], t);

  u64 mask = __ballot(t > 0.0f);
  if (lane == 0) {
    int base = (o * 9 + tap) * 4 + g * 2;
    wb[base]     = (u32)mask;
    wb[base + 1] = (u32)(mask >> 32);
  }
}

// ---------------------------------------------------------------------------
// Kernel 2: activation sign-pack into zero-padded 58x58 bit array.
// Wave lanes = channels; 2 ballots per pixel -> uint4 (128 bits) per pixel.
// Each wave handles 14 consecutive pixels of one row (good line reuse).
__global__ __launch_bounds__(256) void k_apack(
    const float* __restrict__ x, uint4* __restrict__ ab)
{
  int gid  = blockIdx.x * 256 + threadIdx.x;
  int wid  = gid >> 6;                 // 0..7167 (= 32 b * 56 h * 4 quarters)
  int lane = threadIdx.x & 63;
  int q    = wid & 3;
  int bh   = wid >> 2;
  int h    = bh % 56;
  int b    = bh / 56;
  const float* xp = x + (size_t)b * (128 * HW) + h * 56;
  int w0 = q * 14;

#pragma unroll
  for (int j = 0; j < 14; ++j) {
    int w = w0 + j;
    float v0 = xp[(size_t)lane * HW + w];
    float v1 = xp[(size_t)(lane + 64) * HW + w];
    u64 m0 = __ballot(v0 > 0.0f);
    u64 m1 = __ballot(v1 > 0.0f);
    if (lane == 0) {
      size_t pi = ((size_t)b * PADW + (h + 1)) * PADW + (w + 1);
      ab[pi] = make_uint4((u32)m0, (u32)(m0 >> 32), (u32)m1, (u32)(m1 >> 32));
    }
  }
}

// ---------------------------------------------------------------------------
// Kernel 3: popcount conv. Thread = output pixel; loops all 128 out-channels.
// res(o) = 128*nv - 2 * sum_t popc((a_t ^ w_t) & kk_t); out = res * alpha[o].
__global__ __launch_bounds__(256) void k_conv(
    const uint4* __restrict__ ab, const uint4* __restrict__ wbg,
    const float* __restrict__ Alpha, float* __restrict__ out)
{
  __shared__ uint4 swb[1152];
  __shared__ float sal[128];
  int tid = threadIdx.x;
  for (int idx = tid; idx < 1152; idx += 256) swb[idx] = wbg[idx];
  if (tid < 128) sal[tid] = Alpha[tid];
  __syncthreads();

  int p  = blockIdx.x * 256 + tid;     // 0..100351
  int b  = p / HW;
  int hw = p - b * HW;
  int h  = hw / 56;
  int w  = hw - h * 56;

  u32 a[9][4];
  u32 kk[9];
  int nv = 0;
#pragma unroll
  for (int dh = 0; dh < 3; ++dh) {
#pragma unroll
    for (int dw = 0; dw < 3; ++dw) {
      int t  = dh * 3 + dw;
      int hh = h + dh;                 // padded coords
      int ww = w + dw;
      uint4 v = ab[((size_t)b * PADW + hh) * PADW + ww];
      a[t][0] = v.x; a[t][1] = v.y; a[t][2] = v.z; a[t][3] = v.w;
      int valid = (hh >= 1) & (hh <= 56) & (ww >= 1) & (ww <= 56);
      kk[t] = valid ? 0xffffffffu : 0u;
      nv += valid;
    }
  }
  int base = nv * 128;
  float* outp = out + (size_t)b * (128 * HW) + hw;

#pragma unroll 2
  for (int o = 0; o < 128; ++o) {
    int s = 0;
#pragma unroll
    for (int t = 0; t < 9; ++t) {
      uint4 wv = swb[o * 9 + t];
      s += __popc((a[t][0] ^ wv.x) & kk[t]);
      s += __popc((a[t][1] ^ wv.y) & kk[t]);
      s += __popc((a[t][2] ^ wv.z) & kk[t]);
      s += __popc((a[t][3] ^ wv.w) & kk[t]);
    }
    outp[(size_t)o * HW] = (float)(base - 2 * s) * sal[o];
  }
}

// ---------------------------------------------------------------------------
extern "C" void kernel_launch(void* const* d_in, const int* in_sizes, int n_in,
                              void* d_out, int out_size, void* d_ws, size_t ws_size,
                              hipStream_t stream)
{
  const float* x     = (const float*)d_in[0];
  const float* Alpha = (const float*)d_in[1];
  const float* M     = (const float*)d_in[2];
  const float* Z     = (const float*)d_in[3];
  const float* rv    = (const float*)d_in[4];
  float* out         = (float*)d_out;

  u32*   wb = (u32*)d_ws;                            // 4608 u32 = 18432 B
  uint4* ab = (uint4*)((char*)d_ws + 18432);         // 32*58*58 uint4 = 1722368 B

  // zero the padded activation-bit array (borders must be 0)
  hipMemsetAsync(ab, 0, (size_t)32 * PADW * PADW * sizeof(uint4), stream);

  k_wsynth<<<576, 256, 0, stream>>>(M, Z, rv, wb);
  k_apack<<<1792, 256, 0, stream>>>(x, ab);
  k_conv<<<392, 256, 0, stream>>>(ab, (const uint4*)wb, Alpha, out);
}